// Round 1
// baseline (39002.164 us; speedup 1.0000x reference)
//
#include <hip/hip_runtime.h>

#define B_ 8
#define T_ 1024
#define E_ 512
#define H_ 512
#define G_ 2048   // 4*H
#define H2_ 1024

// ---------------- helpers ----------------
__device__ __forceinline__ float sigmoid_f(float x) { return 1.0f / (1.0f + __expf(-x)); }
__device__ __forceinline__ float tanh_f(float x) { return 1.0f - 2.0f / (__expf(2.0f * x) + 1.0f); }

// ---------------- embedding gather ----------------
__global__ __launch_bounds__(256) void k_embed(const int* __restrict__ idx,
                                               const float* __restrict__ emb,
                                               float* __restrict__ x0) {
  int i = blockIdx.x * 256 + threadIdx.x;   // float4 index; total B*T*E/4 = 1,048,576
  int row = i >> 7;                          // 128 float4 per row (E=512)
  int e4 = i & 127;
  int tok = idx[row];
  reinterpret_cast<float4*>(x0)[i] =
      reinterpret_cast<const float4*>(emb)[(size_t)tok * 128 + e4];
}

// ---------------- fp32 GEMM: C[m][n] = sum_k A[m][k]*Bw[n][k] + bias0[n]+bias1[n] ----------------
// tile 128x128, K-step 16, 256 threads, 8x8 micro-tile
__global__ __launch_bounds__(256, 2) void k_gemm(
    const float* __restrict__ A, int lda,
    const float* __restrict__ Bw,   // [N][K] row-major
    const float* __restrict__ bias0, const float* __restrict__ bias1,
    float* __restrict__ C, int ldc, int K) {
  __shared__ float As[16][132];
  __shared__ float Bs[16][132];
  const int bm = blockIdx.x * 128;
  const int bn = blockIdx.y * 128;
  const int tid = threadIdx.x;
  const int tm = (tid & 15) * 8;
  const int tn = (tid >> 4) * 8;
  float acc[8][8];
#pragma unroll
  for (int i = 0; i < 8; ++i)
#pragma unroll
    for (int j = 0; j < 8; ++j) acc[i][j] = 0.f;

  for (int k0 = 0; k0 < K; k0 += 16) {
#pragma unroll
    for (int i = 0; i < 2; ++i) {
      int idx = tid * 2 + i;          // 0..511
      int row = idx >> 2;             // 0..127
      int k4 = (idx & 3) * 4;
      float4 a = *reinterpret_cast<const float4*>(A + (size_t)(bm + row) * lda + k0 + k4);
      As[k4 + 0][row] = a.x; As[k4 + 1][row] = a.y; As[k4 + 2][row] = a.z; As[k4 + 3][row] = a.w;
      float4 b = *reinterpret_cast<const float4*>(Bw + (size_t)(bn + row) * K + k0 + k4);
      Bs[k4 + 0][row] = b.x; Bs[k4 + 1][row] = b.y; Bs[k4 + 2][row] = b.z; Bs[k4 + 3][row] = b.w;
    }
    __syncthreads();
#pragma unroll
    for (int k = 0; k < 16; ++k) {
      float4 a0 = *reinterpret_cast<const float4*>(&As[k][tm]);
      float4 a1 = *reinterpret_cast<const float4*>(&As[k][tm + 4]);
      float4 b0 = *reinterpret_cast<const float4*>(&Bs[k][tn]);
      float4 b1 = *reinterpret_cast<const float4*>(&Bs[k][tn + 4]);
      float av[8] = {a0.x, a0.y, a0.z, a0.w, a1.x, a1.y, a1.z, a1.w};
      float bv[8] = {b0.x, b0.y, b0.z, b0.w, b1.x, b1.y, b1.z, b1.w};
#pragma unroll
      for (int i = 0; i < 8; ++i)
#pragma unroll
        for (int j = 0; j < 8; ++j) acc[i][j] = fmaf(av[i], bv[j], acc[i][j]);
    }
    __syncthreads();
  }
  float bb[8];
#pragma unroll
  for (int j = 0; j < 8; ++j)
    bb[j] = (bias0 ? bias0[bn + tn + j] : 0.f) + (bias1 ? bias1[bn + tn + j] : 0.f);
#pragma unroll
  for (int i = 0; i < 8; ++i) {
    float4 o0, o1;
    o0.x = acc[i][0] + bb[0]; o0.y = acc[i][1] + bb[1];
    o0.z = acc[i][2] + bb[2]; o0.w = acc[i][3] + bb[3];
    o1.x = acc[i][4] + bb[4]; o1.y = acc[i][5] + bb[5];
    o1.z = acc[i][6] + bb[6]; o1.w = acc[i][7] + bb[7];
    float* cp = C + (size_t)(bm + tm + i) * ldc + bn + tn;
    *reinterpret_cast<float4*>(cp) = o0;
    *reinterpret_cast<float4*>(cp + 4) = o1;
  }
}

// ---------------- persistent bidirectional LSTM recurrence (one layer) ----------------
// grid: 128 WGs x 512 threads. WG w: dir = w>>6, slice = w&63 (8 h-indices).
// thread: b = tid&7, cc = (tid>>3)&7 (64-col chunk), rg = tid>>6 (h-offset in slice).
// Flag-array barrier per direction (64 WGs/group), agent-scope atomics.
__device__ __forceinline__ void rec_barrier(int* F, int slice, int target, int tid) {
  __syncthreads();
  if (tid == 0) {
    __threadfence();
    __hip_atomic_store(&F[slice], target, __ATOMIC_RELEASE, __HIP_MEMORY_SCOPE_AGENT);
  }
  if (tid < 64) {
    while (__hip_atomic_load(&F[tid], __ATOMIC_ACQUIRE, __HIP_MEMORY_SCOPE_AGENT) < target) {}
  }
  __syncthreads();
}

__global__ __launch_bounds__(512) void k_lstm(
    const float* __restrict__ xw,    // [2][B*T][2048]  (precomputed x@Wih.T + biases)
    const float* __restrict__ Whh,   // [2][2048][512]
    float* __restrict__ out,         // [B*T][1024], col offset dir*512
    float* __restrict__ hbuf,        // [2 bufs][2 dirs][8][512]
    int* __restrict__ flags)         // [2 dirs][64]
{
  const int wg = blockIdx.x;
  const int dir = wg >> 6;
  const int slice = wg & 63;
  const int tid = threadIdx.x;
  const int b = tid & 7;
  const int cc = (tid >> 3) & 7;
  const int rg = tid >> 6;
  const int hb = slice * 8 + rg;
  const float* xwd = xw + (size_t)dir * (8192ull * 2048ull);
  const float* Wd = Whh + (size_t)dir * (2048ull * 512ull);
  int* F = flags + dir * 64;
  float c_state = 0.f;

  if (cc == 0) hbuf[(size_t)((0 * 2 + dir) * 8 + b) * 512 + hb] = 0.f;
  rec_barrier(F, slice, 1, tid);

  for (int s = 0; s < 1024; ++s) {
    const int t = dir ? (1023 - s) : s;
    const float* Ws = Wd;
    asm volatile("" : "+v"(Ws));  // block LICM from hoisting 64 weight loads out of s-loop
    const float4* hrow = reinterpret_cast<const float4*>(
        hbuf + (size_t)(((s & 1) * 2 + dir) * 8 + b) * 512 + cc * 64);
    float accq[4] = {0.f, 0.f, 0.f, 0.f};
#pragma unroll
    for (int k4 = 0; k4 < 16; ++k4) {
      float4 h4 = hrow[k4];
#pragma unroll
      for (int q = 0; q < 4; ++q) {
        const float4* wr = reinterpret_cast<const float4*>(
            Ws + (size_t)(q * 512 + hb) * 512 + cc * 64);
        float4 w4 = wr[k4];
        accq[q] = fmaf(w4.x, h4.x, accq[q]);
        accq[q] = fmaf(w4.y, h4.y, accq[q]);
        accq[q] = fmaf(w4.z, h4.z, accq[q]);
        accq[q] = fmaf(w4.w, h4.w, accq[q]);
      }
    }
#pragma unroll
    for (int m = 8; m <= 32; m <<= 1) {
#pragma unroll
      for (int q = 0; q < 4; ++q) accq[q] += __shfl_xor(accq[q], m, 64);
    }
    const float* xwrow = xwd + (size_t)(b * 1024 + t) * 2048;
    float gi = accq[0] + xwrow[0 * 512 + hb];
    float gf = accq[1] + xwrow[1 * 512 + hb];
    float gg = accq[2] + xwrow[2 * 512 + hb];
    float go = accq[3] + xwrow[3 * 512 + hb];
    float iv = sigmoid_f(gi), fv = sigmoid_f(gf), gv = tanh_f(gg), ov = sigmoid_f(go);
    c_state = fv * c_state + iv * gv;
    float hv = ov * tanh_f(c_state);
    if (cc == 0) {
      hbuf[(size_t)((((s + 1) & 1) * 2 + dir) * 8 + b) * 512 + hb] = hv;
      out[(size_t)(b * 1024 + t) * 1024 + dir * 512 + hb] = hv;
    }
    rec_barrier(F, slice, s + 2, tid);
  }
}

// ---------------- last-token attention: one WG per (dir, b, head) ----------------
__global__ __launch_bounds__(256) void k_attn(
    const float* __restrict__ out1,
    const float* __restrict__ Kf, const float* __restrict__ Vf,
    const float* __restrict__ Kb, const float* __restrict__ Vb,
    const float* __restrict__ Wqf, const float* __restrict__ Wqb,
    float* __restrict__ ctx) {
  const int dir = blockIdx.x >> 6;
  const int b = (blockIdx.x >> 3) & 7;
  const int head = blockIdx.x & 7;
  const float* Kd = dir ? Kb : Kf;
  const float* Vd = dir ? Vb : Vf;
  const float* Wq = dir ? Wqb : Wqf;
  __shared__ float xs[512];
  __shared__ float qs[64];
  __shared__ float sc[1024];
  __shared__ float red[8];
  __shared__ float pr[4][64];
  const int tid = threadIdx.x;
  for (int k = tid; k < 512; k += 256)
    xs[k] = out1[(size_t)(b * 1024 + 1023) * 1024 + dir * 512 + k];
  __syncthreads();
  {  // q[d] = dot(xs, Wq[head*64+d])
    int d = tid >> 2, part = tid & 3;
    const float* w = Wq + (size_t)(head * 64 + d) * 512;
    float s = 0.f;
    for (int k = part * 4; k < 512; k += 16) {
      float4 w4 = *reinterpret_cast<const float4*>(w + k);
      float4 x4 = *reinterpret_cast<const float4*>(&xs[k]);
      s += w4.x * x4.x + w4.y * x4.y + w4.z * x4.z + w4.w * x4.w;
    }
    s += __shfl_xor(s, 1, 64);
    s += __shfl_xor(s, 2, 64);
    if (part == 0) qs[d] = s;
  }
  __syncthreads();
  float smax = -1e30f;
  float sv[4];
#pragma unroll
  for (int j = 0; j < 4; ++j) {
    int tt = j * 256 + tid;
    const float* krow = Kd + (size_t)(b * 1024 + tt) * 512 + head * 64;
    float s = 0.f;
#pragma unroll
    for (int k = 0; k < 64; k += 4) {
      float4 k4 = *reinterpret_cast<const float4*>(krow + k);
      float4 q4 = *reinterpret_cast<const float4*>(&qs[k]);
      s += k4.x * q4.x + k4.y * q4.y + k4.z * q4.z + k4.w * q4.w;
    }
    s *= 0.125f;  // 1/sqrt(64)
    sv[j] = s;
    smax = fmaxf(smax, s);
  }
#pragma unroll
  for (int m = 1; m <= 32; m <<= 1) smax = fmaxf(smax, __shfl_xor(smax, m, 64));
  if ((tid & 63) == 0) red[tid >> 6] = smax;
  __syncthreads();
  smax = fmaxf(fmaxf(red[0], red[1]), fmaxf(red[2], red[3]));
  float lsum = 0.f;
#pragma unroll
  for (int j = 0; j < 4; ++j) {
    float e = __expf(sv[j] - smax);
    sc[j * 256 + tid] = e;
    lsum += e;
  }
#pragma unroll
  for (int m = 1; m <= 32; m <<= 1) lsum += __shfl_xor(lsum, m, 64);
  if ((tid & 63) == 0) red[4 + (tid >> 6)] = lsum;
  __syncthreads();
  float inv = 1.0f / (red[4] + red[5] + red[6] + red[7]);
  const int d = tid & 63, part = tid >> 6;
  float cacc = 0.f;
  for (int tt = part * 256; tt < part * 256 + 256; ++tt)
    cacc = fmaf(sc[tt], Vd[(size_t)(b * 1024 + tt) * 512 + head * 64 + d], cacc);
  pr[part][d] = cacc;
  __syncthreads();
  if (tid < 64) {
    float r = (pr[0][tid] + pr[1][tid] + pr[2][tid] + pr[3][tid]) * inv;
    ctx[(size_t)(dir * 8 + b) * 512 + head * 64 + tid] = r;
  }
}

// ---------------- layernorm over 1024, one WG per batch row ----------------
__global__ __launch_bounds__(256) void k_ln(const float* __restrict__ X,
                                            const float* __restrict__ g,
                                            const float* __restrict__ be,
                                            float* __restrict__ Y) {
  const int b = blockIdx.x, tid = threadIdx.x;
  __shared__ float red[8];
  float4 v = reinterpret_cast<const float4*>(X + (size_t)b * 1024)[tid];
  float s = v.x + v.y + v.z + v.w;
  float ss = v.x * v.x + v.y * v.y + v.z * v.z + v.w * v.w;
#pragma unroll
  for (int m = 1; m <= 32; m <<= 1) {
    s += __shfl_xor(s, m, 64);
    ss += __shfl_xor(ss, m, 64);
  }
  if ((tid & 63) == 0) { red[tid >> 6] = s; red[4 + (tid >> 6)] = ss; }
  __syncthreads();
  s = red[0] + red[1] + red[2] + red[3];
  ss = red[4] + red[5] + red[6] + red[7];
  float mean = s * (1.f / 1024.f);
  float var = ss * (1.f / 1024.f) - mean * mean;
  float rstd = rsqrtf(var + 1e-5f);
  float4 gv = reinterpret_cast<const float4*>(g)[tid];
  float4 bv = reinterpret_cast<const float4*>(be)[tid];
  float4 o;
  o.x = (v.x - mean) * rstd * gv.x + bv.x;
  o.y = (v.y - mean) * rstd * gv.y + bv.y;
  o.z = (v.z - mean) * rstd * gv.z + bv.z;
  o.w = (v.w - mean) * rstd * gv.w + bv.w;
  reinterpret_cast<float4*>(Y + (size_t)b * 1024)[tid] = o;
}

// ---------------- small row-dot: Y[m][n] = act(dot(X[m], W[n]) + bias[n]) ----------------
// grid.x = m, grid.y = n-chunks of 64; 256 threads (4 lanes per n)
__global__ __launch_bounds__(256) void k_rowdot(
    const float* __restrict__ X, int ldx,
    const float* __restrict__ W,
    const float* __restrict__ bias,
    float* __restrict__ Y, int ldy,
    int N, int K, int act) {
  __shared__ float xs[2048];
  const int m = blockIdx.x;
  const int n0 = blockIdx.y * 64;
  const int tid = threadIdx.x;
  for (int k = tid * 4; k < K; k += 1024)
    *reinterpret_cast<float4*>(&xs[k]) =
        *reinterpret_cast<const float4*>(X + (size_t)m * ldx + k);
  __syncthreads();
  const int nl = tid >> 2, part = tid & 3;
  const int n = n0 + nl;
  float s = 0.f;
  if (n < N) {
    const float* w = W + (size_t)n * K;
    for (int k = part * 4; k < K; k += 16) {
      float4 w4 = *reinterpret_cast<const float4*>(w + k);
      float4 x4 = *reinterpret_cast<const float4*>(&xs[k]);
      s += w4.x * x4.x + w4.y * x4.y + w4.z * x4.z + w4.w * x4.w;
    }
  }
  s += __shfl_xor(s, 1, 64);
  s += __shfl_xor(s, 2, 64);
  if (part == 0 && n < N) {
    if (bias) s += bias[n];
    if (act == 1) s = fmaxf(s, 0.f);
    Y[(size_t)m * ldy + n] = s;
  }
}

// ---------------- launch ----------------
extern "C" void kernel_launch(void* const* d_in, const int* in_sizes, int n_in,
                              void* d_out, int out_size, void* d_ws, size_t ws_size,
                              hipStream_t stream) {
  const int* in_idx = (const int*)d_in[0];
  const float* emb  = (const float*)d_in[1];
  const float* Wih0 = (const float*)d_in[2];
  const float* Whh0 = (const float*)d_in[3];
  const float* bih0 = (const float*)d_in[4];
  const float* bhh0 = (const float*)d_in[5];
  const float* Wih1 = (const float*)d_in[6];
  const float* Whh1 = (const float*)d_in[7];
  const float* bih1 = (const float*)d_in[8];
  const float* bhh1 = (const float*)d_in[9];
  const float* fWq = (const float*)d_in[10];
  const float* fWk = (const float*)d_in[11];
  const float* fWv = (const float*)d_in[12];
  const float* fWo = (const float*)d_in[13];
  const float* fbo = (const float*)d_in[14];
  const float* bWq = (const float*)d_in[15];
  const float* bWk = (const float*)d_in[16];
  const float* bWv = (const float*)d_in[17];
  const float* bWo = (const float*)d_in[18];
  const float* bbo = (const float*)d_in[19];
  const float* ln_g = (const float*)d_in[20];
  const float* ln_b = (const float*)d_in[21];
  const float* ffW1 = (const float*)d_in[22];
  const float* ffb1 = (const float*)d_in[23];
  const float* ffW2 = (const float*)d_in[24];
  const float* ffb2 = (const float*)d_in[25];
  const float* outW = (const float*)d_in[26];
  const float* outb = (const float*)d_in[27];
  float* out = (float*)d_out;

  char* ws = (char*)d_ws;
  float* xw   = (float*)(ws + 0);           // 2*8192*2048 f = 128 MiB
  float* x0   = (float*)(ws + 134217728);   // 16 MiB
  float* out0 = (float*)(ws + 150994944);   // 32 MiB
  float* out1 = (float*)(ws + 184549376);   // 32 MiB
  // K/V alias the xw region (xw is dead once layer-1 recurrence finishes)
  float* Kf = (float*)(ws + 0);
  float* Vf = (float*)(ws + 16777216);
  float* Kb = (float*)(ws + 33554432);
  float* Vb = (float*)(ws + 50331648);
  float* hbuf = (float*)(ws + 218103808);   // 64 KiB
  int*   flags = (int*)(ws + 218169344);    // 1 KiB (layer0: +0, layer1: +128 ints)
  float* ctx  = (float*)(ws + 218170368);   // 32 KiB
  float* xcat = (float*)(ws + 218203136);   // 32 KiB
  float* xln  = (float*)(ws + 218235904);   // 32 KiB
  float* h1   = (float*)(ws + 218268672);   // 64 KiB
  float* h2   = (float*)(ws + 218334208);   // 32 KiB

  hipMemsetAsync(flags, 0, 1024, stream);
  k_embed<<<4096, 256, 0, stream>>>(in_idx, emb, x0);

  dim3 g0(64, 16);
  k_gemm<<<g0, 256, 0, stream>>>(x0, 512, Wih0,              bih0,        bhh0,        xw,                         2048, 512);
  k_gemm<<<g0, 256, 0, stream>>>(x0, 512, Wih0 + 2048 * 512, bih0 + 2048, bhh0 + 2048, xw + 8192ull * 2048ull,     2048, 512);
  k_lstm<<<128, 512, 0, stream>>>(xw, Whh0, out0, hbuf, flags);

  k_gemm<<<g0, 256, 0, stream>>>(out0, 1024, Wih1,               bih1,        bhh1,        xw,                     2048, 1024);
  k_gemm<<<g0, 256, 0, stream>>>(out0, 1024, Wih1 + 2048 * 1024, bih1 + 2048, bhh1 + 2048, xw + 8192ull * 2048ull, 2048, 1024);
  k_lstm<<<128, 512, 0, stream>>>(xw, Whh1, out1, hbuf, flags + 128);

  dim3 gkv(64, 4);
  k_gemm<<<gkv, 256, 0, stream>>>(out1,       1024, fWk, nullptr, nullptr, Kf, 512, 512);
  k_gemm<<<gkv, 256, 0, stream>>>(out1,       1024, fWv, nullptr, nullptr, Vf, 512, 512);
  k_gemm<<<gkv, 256, 0, stream>>>(out1 + 512, 1024, bWk, nullptr, nullptr, Kb, 512, 512);
  k_gemm<<<gkv, 256, 0, stream>>>(out1 + 512, 1024, bWv, nullptr, nullptr, Vb, 512, 512);

  k_attn<<<128, 256, 0, stream>>>(out1, Kf, Vf, Kb, Vb, fWq, bWq, ctx);

  dim3 gpo(8, 8);
  k_rowdot<<<gpo, 256, 0, stream>>>(ctx,             512, fWo, fbo, xcat,       1024, 512, 512, 0);
  k_rowdot<<<gpo, 256, 0, stream>>>(ctx + 8 * 512,   512, bWo, bbo, xcat + 512, 1024, 512, 512, 0);
  k_ln<<<8, 256, 0, stream>>>(xcat, ln_g, ln_b, xln);
  k_rowdot<<<dim3(8, 32), 256, 0, stream>>>(xln, 1024, ffW1, ffb1, h1, 2048, 2048, 1024, 1);
  k_rowdot<<<dim3(8, 16), 256, 0, stream>>>(h1, 2048, ffW2, ffb2, h2, 1024, 1024, 2048, 0);
  k_rowdot<<<dim3(8, 1), 256, 0, stream>>>(h2, 1024, outW, outb, out, 6, 6, 1024, 0);
}

// Round 2
// 23689.633 us; speedup vs baseline: 1.6464x; 1.6464x over previous
//
#include <hip/hip_runtime.h>

#define B_ 8
#define T_ 1024
#define E_ 512
#define H_ 512
#define G_ 2048   // 4*H
#define H2_ 1024

// ---------------- helpers ----------------
__device__ __forceinline__ float sigmoid_f(float x) { return 1.0f / (1.0f + __expf(-x)); }
__device__ __forceinline__ float tanh_f(float x) { return 1.0f - 2.0f / (__expf(2.0f * x) + 1.0f); }

// ---------------- embedding gather ----------------
__global__ __launch_bounds__(256) void k_embed(const int* __restrict__ idx,
                                               const float* __restrict__ emb,
                                               float* __restrict__ x0) {
  int i = blockIdx.x * 256 + threadIdx.x;   // float4 index; total B*T*E/4 = 1,048,576
  int row = i >> 7;                          // 128 float4 per row (E=512)
  int e4 = i & 127;
  int tok = idx[row];
  reinterpret_cast<float4*>(x0)[i] =
      reinterpret_cast<const float4*>(emb)[(size_t)tok * 128 + e4];
}

// ---------------- fp32 GEMM: C[m][n] = sum_k A[m][k]*Bw[n][k] + bias0[n]+bias1[n] ----------------
// tile 128x128, K-step 16, 256 threads, 8x8 micro-tile
__global__ __launch_bounds__(256, 2) void k_gemm(
    const float* __restrict__ A, int lda,
    const float* __restrict__ Bw,   // [N][K] row-major
    const float* __restrict__ bias0, const float* __restrict__ bias1,
    float* __restrict__ C, int ldc, int K) {
  __shared__ float As[16][132];
  __shared__ float Bs[16][132];
  const int bm = blockIdx.x * 128;
  const int bn = blockIdx.y * 128;
  const int tid = threadIdx.x;
  const int tm = (tid & 15) * 8;
  const int tn = (tid >> 4) * 8;
  float acc[8][8];
#pragma unroll
  for (int i = 0; i < 8; ++i)
#pragma unroll
    for (int j = 0; j < 8; ++j) acc[i][j] = 0.f;

  for (int k0 = 0; k0 < K; k0 += 16) {
#pragma unroll
    for (int i = 0; i < 2; ++i) {
      int idx = tid * 2 + i;          // 0..511
      int row = idx >> 2;             // 0..127
      int k4 = (idx & 3) * 4;
      float4 a = *reinterpret_cast<const float4*>(A + (size_t)(bm + row) * lda + k0 + k4);
      As[k4 + 0][row] = a.x; As[k4 + 1][row] = a.y; As[k4 + 2][row] = a.z; As[k4 + 3][row] = a.w;
      float4 b = *reinterpret_cast<const float4*>(Bw + (size_t)(bn + row) * K + k0 + k4);
      Bs[k4 + 0][row] = b.x; Bs[k4 + 1][row] = b.y; Bs[k4 + 2][row] = b.z; Bs[k4 + 3][row] = b.w;
    }
    __syncthreads();
#pragma unroll
    for (int k = 0; k < 16; ++k) {
      float4 a0 = *reinterpret_cast<const float4*>(&As[k][tm]);
      float4 a1 = *reinterpret_cast<const float4*>(&As[k][tm + 4]);
      float4 b0 = *reinterpret_cast<const float4*>(&Bs[k][tn]);
      float4 b1 = *reinterpret_cast<const float4*>(&Bs[k][tn + 4]);
      float av[8] = {a0.x, a0.y, a0.z, a0.w, a1.x, a1.y, a1.z, a1.w};
      float bv[8] = {b0.x, b0.y, b0.z, b0.w, b1.x, b1.y, b1.z, b1.w};
#pragma unroll
      for (int i = 0; i < 8; ++i)
#pragma unroll
        for (int j = 0; j < 8; ++j) acc[i][j] = fmaf(av[i], bv[j], acc[i][j]);
    }
    __syncthreads();
  }
  float bb[8];
#pragma unroll
  for (int j = 0; j < 8; ++j)
    bb[j] = (bias0 ? bias0[bn + tn + j] : 0.f) + (bias1 ? bias1[bn + tn + j] : 0.f);
#pragma unroll
  for (int i = 0; i < 8; ++i) {
    float4 o0, o1;
    o0.x = acc[i][0] + bb[0]; o0.y = acc[i][1] + bb[1];
    o0.z = acc[i][2] + bb[2]; o0.w = acc[i][3] + bb[3];
    o1.x = acc[i][4] + bb[4]; o1.y = acc[i][5] + bb[5];
    o1.z = acc[i][6] + bb[6]; o1.w = acc[i][7] + bb[7];
    float* cp = C + (size_t)(bm + tm + i) * ldc + bn + tn;
    *reinterpret_cast<float4*>(cp) = o0;
    *reinterpret_cast<float4*>(cp + 4) = o1;
  }
}

// ---------------- persistent bidirectional LSTM recurrence (one layer) ----------------
// grid: 128 WGs x 512 threads. WG w: dir = w>>6, slice = w&63.
// WG owns 32 gate rows: row_global(rl) = (rl>>3)*512 + slice*8 + (rl&7), rl = q*8+i.
// Weights REGISTER-RESIDENT: thread (kp=tid&31, rg=(tid>>5)&3, bq=tid>>7) holds
// rows rl = rg*8+r (r=0..7), k-slice [kp*16, kp*16+16) -> 32 float4 in VGPRs.
// Per step: h staged global->LDS in [j][b][kp] float2 layout (2-way bank = free),
// 256 FMA/thread, 5-stage shfl_xor butterfly over kp lanes, 64 threads do gates.
__device__ __forceinline__ void rec_barrier(int* F, int slice, int target, int tid) {
  __syncthreads();
  if (tid == 0) {
    __threadfence();
    __hip_atomic_store(&F[slice], target, __ATOMIC_RELEASE, __HIP_MEMORY_SCOPE_AGENT);
  }
  if (tid < 64) {
    while (__hip_atomic_load(&F[tid], __ATOMIC_ACQUIRE, __HIP_MEMORY_SCOPE_AGENT) < target) {}
  }
  __syncthreads();
}

__global__ __launch_bounds__(512) void k_lstm(
    const float* __restrict__ xw,    // [2][B*T][2048]  (precomputed x@Wih.T + biases)
    const float* __restrict__ Whh,   // [2][2048][512]
    float* __restrict__ out,         // [B*T][1024], col offset dir*512
    float* __restrict__ hbuf,        // [2 bufs][2 dirs][8][512]
    int* __restrict__ flags)         // [2 dirs][64]
{
  const int wg = blockIdx.x;
  const int dir = wg >> 6;
  const int slice = wg & 63;
  const int tid = threadIdx.x;
  const int kp = tid & 31;
  const int rg = (tid >> 5) & 3;
  const int bq = tid >> 7;

  __shared__ float hs[4096];        // float2 slots [j(8)][b(8)][kp(32)]
  __shared__ float gmat[32 * 9];    // [rl(32)][b(8)] padded to 9

  const float* xwd = xw + (size_t)dir * (8192ull * 2048ull);
  const float* Wd = Whh + (size_t)dir * (2048ull * 512ull);
  int* F = flags + dir * 64;

  // ---- one-time weight preload into registers ----
  float4 w4[8][4];
#pragma unroll
  for (int r = 0; r < 8; ++r) {
    int rl = rg * 8 + r;
    int row = ((rl >> 3) << 9) + slice * 8 + (rl & 7);
    const float4* wp = reinterpret_cast<const float4*>(Wd + (size_t)row * 512 + kp * 16);
#pragma unroll
    for (int q = 0; q < 4; ++q) w4[r][q] = wp[q];
  }

  const int ii = tid & 7, bb = tid >> 3;   // roles for tid<64 epilogue threads
  float c_state = 0.f;
  if (tid < 64) hbuf[(size_t)((0 * 2 + dir) * 8 + bb) * 512 + slice * 8 + ii] = 0.f;
  rec_barrier(F, slice, 1, tid);

  for (int s = 0; s < 1024; ++s) {
    const int t = dir ? (1023 - s) : s;

    // xw prefetch (independent of barrier-fresh data; overlaps staging latency)
    float xg0 = 0.f, xg1 = 0.f, xg2 = 0.f, xg3 = 0.f;
    if (tid < 64) {
      const float* xr = xwd + (size_t)(bb * 1024 + t) * 2048 + slice * 8 + ii;
      xg0 = xr[0]; xg1 = xr[512]; xg2 = xr[1024]; xg3 = xr[1536];
    }

    // ---- stage h(s): global -> LDS [j][b][kp] float2 layout ----
    {
      const float* hsrc = hbuf + (size_t)(((s & 1) * 2 + dir) * 8) * 512;
#pragma unroll
      for (int i = 0; i < 2; ++i) {
        int g = tid + i * 512;          // 0..1023 float4s
        int b = g >> 7, f = g & 127;    // f = k/4
        float4 v = *reinterpret_cast<const float4*>(hsrc + b * 512 + f * 4);
        int j0 = (f & 3) * 2;
        int base = ((j0 * 8 + b) * 32 + (f >> 2)) * 2;
        *reinterpret_cast<float2*>(&hs[base]) = make_float2(v.x, v.y);
        *reinterpret_cast<float2*>(&hs[base + 512]) = make_float2(v.z, v.w);  // j0+1
      }
    }
    __syncthreads();

    // ---- partial dot products: acc[r][bl] over this thread's 16-k slice ----
    float acc[8][2];
#pragma unroll
    for (int r = 0; r < 8; ++r) { acc[r][0] = 0.f; acc[r][1] = 0.f; }
#pragma unroll
    for (int bl = 0; bl < 2; ++bl) {
      const int b = bq * 2 + bl;
      const int hbase = (b * 32 + kp) * 2;
#pragma unroll
      for (int j = 0; j < 8; ++j) {
        float2 hv = *reinterpret_cast<const float2*>(&hs[hbase + j * 512]);
#pragma unroll
        for (int r = 0; r < 8; ++r) {
          const float4& W = w4[r][j >> 1];
          float wx = (j & 1) ? W.z : W.x;
          float wy = (j & 1) ? W.w : W.y;
          acc[r][bl] = fmaf(wx, hv.x, fmaf(wy, hv.y, acc[r][bl]));
        }
      }
    }

    // ---- butterfly all-reduce over the 32 kp lanes (bits 0..4 of lane id) ----
#pragma unroll
    for (int m = 1; m <= 16; m <<= 1) {
#pragma unroll
      for (int r = 0; r < 8; ++r) {
        acc[r][0] += __shfl_xor(acc[r][0], m, 64);
        acc[r][1] += __shfl_xor(acc[r][1], m, 64);
      }
    }

    // ---- scatter reduced gates to gmat: lane kp<16 writes (r=kp>>1, bl=kp&1) ----
    if (kp < 16) {
      float val = acc[0][0];
#pragma unroll
      for (int r = 0; r < 8; ++r)
#pragma unroll
        for (int bl = 0; bl < 2; ++bl)
          if (kp == r * 2 + bl) val = acc[r][bl];
      gmat[(rg * 8 + (kp >> 1)) * 9 + (bq * 2 + (kp & 1))] = val;
    }
    __syncthreads();

    // ---- gate nonlinearity + state update (64 threads own (i,b) cells) ----
    if (tid < 64) {
      float gi = gmat[(0 * 8 + ii) * 9 + bb] + xg0;
      float gf = gmat[(1 * 8 + ii) * 9 + bb] + xg1;
      float gg = gmat[(2 * 8 + ii) * 9 + bb] + xg2;
      float go = gmat[(3 * 8 + ii) * 9 + bb] + xg3;
      float iv = sigmoid_f(gi), fv = sigmoid_f(gf), gv = tanh_f(gg), ov = sigmoid_f(go);
      c_state = fv * c_state + iv * gv;
      float hv = ov * tanh_f(c_state);
      hbuf[(size_t)((((s + 1) & 1) * 2 + dir) * 8 + bb) * 512 + slice * 8 + ii] = hv;
      out[(size_t)(bb * 1024 + t) * 1024 + dir * 512 + slice * 8 + ii] = hv;
    }
    rec_barrier(F, slice, s + 2, tid);
  }
}

// ---------------- last-token attention: one WG per (dir, b, head) ----------------
__global__ __launch_bounds__(256) void k_attn(
    const float* __restrict__ out1,
    const float* __restrict__ Kf, const float* __restrict__ Vf,
    const float* __restrict__ Kb, const float* __restrict__ Vb,
    const float* __restrict__ Wqf, const float* __restrict__ Wqb,
    float* __restrict__ ctx) {
  const int dir = blockIdx.x >> 6;
  const int b = (blockIdx.x >> 3) & 7;
  const int head = blockIdx.x & 7;
  const float* Kd = dir ? Kb : Kf;
  const float* Vd = dir ? Vb : Vf;
  const float* Wq = dir ? Wqb : Wqf;
  __shared__ float xs[512];
  __shared__ float qs[64];
  __shared__ float sc[1024];
  __shared__ float red[8];
  __shared__ float pr[4][64];
  const int tid = threadIdx.x;
  for (int k = tid; k < 512; k += 256)
    xs[k] = out1[(size_t)(b * 1024 + 1023) * 1024 + dir * 512 + k];
  __syncthreads();
  {  // q[d] = dot(xs, Wq[head*64+d])
    int d = tid >> 2, part = tid & 3;
    const float* w = Wq + (size_t)(head * 64 + d) * 512;
    float s = 0.f;
    for (int k = part * 4; k < 512; k += 16) {
      float4 w4 = *reinterpret_cast<const float4*>(w + k);
      float4 x4 = *reinterpret_cast<const float4*>(&xs[k]);
      s += w4.x * x4.x + w4.y * x4.y + w4.z * x4.z + w4.w * x4.w;
    }
    s += __shfl_xor(s, 1, 64);
    s += __shfl_xor(s, 2, 64);
    if (part == 0) qs[d] = s;
  }
  __syncthreads();
  float smax = -1e30f;
  float sv[4];
#pragma unroll
  for (int j = 0; j < 4; ++j) {
    int tt = j * 256 + tid;
    const float* krow = Kd + (size_t)(b * 1024 + tt) * 512 + head * 64;
    float s = 0.f;
#pragma unroll
    for (int k = 0; k < 64; k += 4) {
      float4 k4 = *reinterpret_cast<const float4*>(krow + k);
      float4 q4 = *reinterpret_cast<const float4*>(&qs[k]);
      s += k4.x * q4.x + k4.y * q4.y + k4.z * q4.z + k4.w * q4.w;
    }
    s *= 0.125f;  // 1/sqrt(64)
    sv[j] = s;
    smax = fmaxf(smax, s);
  }
#pragma unroll
  for (int m = 1; m <= 32; m <<= 1) smax = fmaxf(smax, __shfl_xor(smax, m, 64));
  if ((tid & 63) == 0) red[tid >> 6] = smax;
  __syncthreads();
  smax = fmaxf(fmaxf(red[0], red[1]), fmaxf(red[2], red[3]));
  float lsum = 0.f;
#pragma unroll
  for (int j = 0; j < 4; ++j) {
    float e = __expf(sv[j] - smax);
    sc[j * 256 + tid] = e;
    lsum += e;
  }
#pragma unroll
  for (int m = 1; m <= 32; m <<= 1) lsum += __shfl_xor(lsum, m, 64);
  if ((tid & 63) == 0) red[4 + (tid >> 6)] = lsum;
  __syncthreads();
  float inv = 1.0f / (red[4] + red[5] + red[6] + red[7]);
  const int d = tid & 63, part = tid >> 6;
  float cacc = 0.f;
  for (int tt = part * 256; tt < part * 256 + 256; ++tt)
    cacc = fmaf(sc[tt], Vd[(size_t)(b * 1024 + tt) * 512 + head * 64 + d], cacc);
  pr[part][d] = cacc;
  __syncthreads();
  if (tid < 64) {
    float r = (pr[0][tid] + pr[1][tid] + pr[2][tid] + pr[3][tid]) * inv;
    ctx[(size_t)(dir * 8 + b) * 512 + head * 64 + tid] = r;
  }
}

// ---------------- layernorm over 1024, one WG per batch row ----------------
__global__ __launch_bounds__(256) void k_ln(const float* __restrict__ X,
                                            const float* __restrict__ g,
                                            const float* __restrict__ be,
                                            float* __restrict__ Y) {
  const int b = blockIdx.x, tid = threadIdx.x;
  __shared__ float red[8];
  float4 v = reinterpret_cast<const float4*>(X + (size_t)b * 1024)[tid];
  float s = v.x + v.y + v.z + v.w;
  float ss = v.x * v.x + v.y * v.y + v.z * v.z + v.w * v.w;
#pragma unroll
  for (int m = 1; m <= 32; m <<= 1) {
    s += __shfl_xor(s, m, 64);
    ss += __shfl_xor(ss, m, 64);
  }
  if ((tid & 63) == 0) { red[tid >> 6] = s; red[4 + (tid >> 6)] = ss; }
  __syncthreads();
  s = red[0] + red[1] + red[2] + red[3];
  ss = red[4] + red[5] + red[6] + red[7];
  float mean = s * (1.f / 1024.f);
  float var = ss * (1.f / 1024.f) - mean * mean;
  float rstd = rsqrtf(var + 1e-5f);
  float4 gv = reinterpret_cast<const float4*>(g)[tid];
  float4 bv = reinterpret_cast<const float4*>(be)[tid];
  float4 o;
  o.x = (v.x - mean) * rstd * gv.x + bv.x;
  o.y = (v.y - mean) * rstd * gv.y + bv.y;
  o.z = (v.z - mean) * rstd * gv.z + bv.z;
  o.w = (v.w - mean) * rstd * gv.w + bv.w;
  reinterpret_cast<float4*>(Y + (size_t)b * 1024)[tid] = o;
}

// ---------------- small row-dot: Y[m][n] = act(dot(X[m], W[n]) + bias[n]) ----------------
__global__ __launch_bounds__(256) void k_rowdot(
    const float* __restrict__ X, int ldx,
    const float* __restrict__ W,
    const float* __restrict__ bias,
    float* __restrict__ Y, int ldy,
    int N, int K, int act) {
  __shared__ float xs[2048];
  const int m = blockIdx.x;
  const int n0 = blockIdx.y * 64;
  const int tid = threadIdx.x;
  for (int k = tid * 4; k < K; k += 1024)
    *reinterpret_cast<float4*>(&xs[k]) =
        *reinterpret_cast<const float4*>(X + (size_t)m * ldx + k);
  __syncthreads();
  const int nl = tid >> 2, part = tid & 3;
  const int n = n0 + nl;
  float s = 0.f;
  if (n < N) {
    const float* w = W + (size_t)n * K;
    for (int k = part * 4; k < K; k += 16) {
      float4 w4 = *reinterpret_cast<const float4*>(w + k);
      float4 x4 = *reinterpret_cast<const float4*>(&xs[k]);
      s += w4.x * x4.x + w4.y * x4.y + w4.z * x4.z + w4.w * x4.w;
    }
  }
  s += __shfl_xor(s, 1, 64);
  s += __shfl_xor(s, 2, 64);
  if (part == 0 && n < N) {
    if (bias) s += bias[n];
    if (act == 1) s = fmaxf(s, 0.f);
    Y[(size_t)m * ldy + n] = s;
  }
}

// ---------------- launch ----------------
extern "C" void kernel_launch(void* const* d_in, const int* in_sizes, int n_in,
                              void* d_out, int out_size, void* d_ws, size_t ws_size,
                              hipStream_t stream) {
  const int* in_idx = (const int*)d_in[0];
  const float* emb  = (const float*)d_in[1];
  const float* Wih0 = (const float*)d_in[2];
  const float* Whh0 = (const float*)d_in[3];
  const float* bih0 = (const float*)d_in[4];
  const float* bhh0 = (const float*)d_in[5];
  const float* Wih1 = (const float*)d_in[6];
  const float* Whh1 = (const float*)d_in[7];
  const float* bih1 = (const float*)d_in[8];
  const float* bhh1 = (const float*)d_in[9];
  const float* fWq = (const float*)d_in[10];
  const float* fWk = (const float*)d_in[11];
  const float* fWv = (const float*)d_in[12];
  const float* fWo = (const float*)d_in[13];
  const float* fbo = (const float*)d_in[14];
  const float* bWq = (const float*)d_in[15];
  const float* bWk = (const float*)d_in[16];
  const float* bWv = (const float*)d_in[17];
  const float* bWo = (const float*)d_in[18];
  const float* bbo = (const float*)d_in[19];
  const float* ln_g = (const float*)d_in[20];
  const float* ln_b = (const float*)d_in[21];
  const float* ffW1 = (const float*)d_in[22];
  const float* ffb1 = (const float*)d_in[23];
  const float* ffW2 = (const float*)d_in[24];
  const float* ffb2 = (const float*)d_in[25];
  const float* outW = (const float*)d_in[26];
  const float* outb = (const float*)d_in[27];
  float* out = (float*)d_out;

  char* ws = (char*)d_ws;
  float* xw   = (float*)(ws + 0);           // 2*8192*2048 f = 128 MiB
  float* x0   = (float*)(ws + 134217728);   // 16 MiB
  float* out0 = (float*)(ws + 150994944);   // 32 MiB
  float* out1 = (float*)(ws + 184549376);   // 32 MiB
  // K/V alias the xw region (xw is dead once layer-1 recurrence finishes)
  float* Kf = (float*)(ws + 0);
  float* Vf = (float*)(ws + 16777216);
  float* Kb = (float*)(ws + 33554432);
  float* Vb = (float*)(ws + 50331648);
  float* hbuf = (float*)(ws + 218103808);   // 64 KiB
  int*   flags = (int*)(ws + 218169344);    // 1 KiB (layer0: +0, layer1: +128 ints)
  float* ctx  = (float*)(ws + 218170368);   // 32 KiB
  float* xcat = (float*)(ws + 218203136);   // 32 KiB
  float* xln  = (float*)(ws + 218235904);   // 32 KiB
  float* h1   = (float*)(ws + 218268672);   // 64 KiB
  float* h2   = (float*)(ws + 218334208);   // 32 KiB

  hipMemsetAsync(flags, 0, 1024, stream);
  k_embed<<<4096, 256, 0, stream>>>(in_idx, emb, x0);

  dim3 g0(64, 16);
  k_gemm<<<g0, 256, 0, stream>>>(x0, 512, Wih0,              bih0,        bhh0,        xw,                         2048, 512);
  k_gemm<<<g0, 256, 0, stream>>>(x0, 512, Wih0 + 2048 * 512, bih0 + 2048, bhh0 + 2048, xw + 8192ull * 2048ull,     2048, 512);
  k_lstm<<<128, 512, 0, stream>>>(xw, Whh0, out0, hbuf, flags);

  k_gemm<<<g0, 256, 0, stream>>>(out0, 1024, Wih1,               bih1,        bhh1,        xw,                     2048, 1024);
  k_gemm<<<g0, 256, 0, stream>>>(out0, 1024, Wih1 + 2048 * 1024, bih1 + 2048, bhh1 + 2048, xw + 8192ull * 2048ull, 2048, 1024);
  k_lstm<<<128, 512, 0, stream>>>(xw, Whh1, out1, hbuf, flags + 128);

  dim3 gkv(64, 4);
  k_gemm<<<gkv, 256, 0, stream>>>(out1,       1024, fWk, nullptr, nullptr, Kf, 512, 512);
  k_gemm<<<gkv, 256, 0, stream>>>(out1,       1024, fWv, nullptr, nullptr, Vf, 512, 512);
  k_gemm<<<gkv, 256, 0, stream>>>(out1 + 512, 1024, bWk, nullptr, nullptr, Kb, 512, 512);
  k_gemm<<<gkv, 256, 0, stream>>>(out1 + 512, 1024, bWv, nullptr, nullptr, Vb, 512, 512);

  k_attn<<<128, 256, 0, stream>>>(out1, Kf, Vf, Kb, Vb, fWq, bWq, ctx);

  dim3 gpo(8, 8);
  k_rowdot<<<gpo, 256, 0, stream>>>(ctx,             512, fWo, fbo, xcat,       1024, 512, 512, 0);
  k_rowdot<<<gpo, 256, 0, stream>>>(ctx + 8 * 512,   512, bWo, bbo, xcat + 512, 1024, 512, 512, 0);
  k_ln<<<8, 256, 0, stream>>>(xcat, ln_g, ln_b, xln);
  k_rowdot<<<dim3(8, 32), 256, 0, stream>>>(xln, 1024, ffW1, ffb1, h1, 2048, 2048, 1024, 1);
  k_rowdot<<<dim3(8, 16), 256, 0, stream>>>(h1, 2048, ffW2, ffb2, h2, 1024, 1024, 2048, 0);
  k_rowdot<<<dim3(8, 1), 256, 0, stream>>>(h2, 1024, outW, outb, out, 6, 6, 1024, 0);
}